// Round 14
// baseline (125.913 us; speedup 1.0000x reference)
//
#include <hip/hip_runtime.h>
#include <hip/hip_bf16.h>

typedef __bf16 bf16_t;
typedef bf16_t bf16x4_t __attribute__((ext_vector_type(4)));
typedef bf16_t bf16x8_t __attribute__((ext_vector_type(8)));
typedef float f32x4_t __attribute__((ext_vector_type(4)));
typedef float f32x16_t __attribute__((ext_vector_type(16)));

constexpr int kB = 2, kN1 = 1536, kN2 = 512, kN = 2048, kC = 1024, kH = 16, kD = 64;
constexpr int BK = 64, LDT = 72;

__device__ inline uint32_t pack2bf(float a, float b) {
  union { bf16_t h[2]; uint32_t u; } t;
  t.h[0] = (bf16_t)a; t.h[1] = (bf16_t)b;
  return t.u;
}
__device__ inline void pl32_swap(uint32_t& a, uint32_t& b) {
  asm volatile("v_permlane32_swap_b32 %0, %1" : "+v"(a), "+v"(b));
}
__device__ __forceinline__ void gl16(const bf16_t* g, bf16_t* l) {
  __builtin_amdgcn_global_load_lds(
      (const __attribute__((address_space(1))) unsigned int*)g,
      (__attribute__((address_space(3))) unsigned int*)l, 16, 0, 0);
}

// ---------------- one-time f32 -> bf16 conversion ----------------
__global__ __launch_bounds__(256)
void cvt_bf16(const float* __restrict__ x, const float* __restrict__ y,
              const float* __restrict__ wqx, const float* __restrict__ wqa,
              const float* __restrict__ wpx, const float* __restrict__ wpa,
              bf16_t* __restrict__ Xb, bf16_t* __restrict__ Wq, bf16_t* __restrict__ Wp)
{
  const int bid = blockIdx.x;
  const float* src; bf16_t* dst; size_t off;
  if (bid < 192)      { src = x;   dst = Xb;           off = (size_t)bid * 16384; }
  else if (bid < 256) { src = y;   dst = Xb + 3145728; off = (size_t)(bid - 192) * 16384; }
  else if (bid < 448) { src = wqx; dst = Wq;           off = (size_t)(bid - 256) * 16384; }
  else if (bid < 640) { src = wqa; dst = Wq + 3145728; off = (size_t)(bid - 448) * 16384; }
  else if (bid < 704) { src = wpx; dst = Wp;           off = (size_t)(bid - 640) * 16384; }
  else                { src = wpa; dst = Wp + 1048576; off = (size_t)(bid - 704) * 16384; }
  src += off; dst += off;
  const int t = threadIdx.x;
  #pragma unroll
  for (int i = 0; i < 16; ++i) {
    const int e = (t + i * 256) * 4;
    f32x4_t v = *(const f32x4_t*)(src + e);
    bf16x4_t o;
    #pragma unroll
    for (int j = 0; j < 4; ++j) o[j] = (bf16_t)v[j];
    *(bf16x4_t*)(dst + e) = o;
  }
}

// ---- QKV GEMM: 128x128, BK=32, 3-stage buffers (48KB -> 3 blocks/CU),
//      raw barrier + counted vmcnt(4); swizzle period widened to 8 rows ----
__global__ __launch_bounds__(256, 3)
void qkv_gemm(const bf16_t* __restrict__ Xb, const bf16_t* __restrict__ Wq,
              const float* __restrict__ cos1, const float* __restrict__ sin1,
              const float* __restrict__ cos2, const float* __restrict__ sin2,
              const float* __restrict__ xs_qw, const float* __restrict__ xs_kw,
              const float* __restrict__ au_qw, const float* __restrict__ au_kw,
              bf16_t* __restrict__ Qb, bf16_t* __restrict__ Kb, bf16_t* __restrict__ Vt)
{
  __shared__ __align__(16) bf16_t smem[24576];  // A bufs x3 [0,12288) | B bufs x3 [12288,24576)
  const int tid = threadIdx.x, lane = tid & 63, w = tid >> 6;
  const int wr = w >> 1, wc = w & 1;
  const int bm = blockIdx.x, bn = blockIdx.y;
  const int l15 = lane & 15, l4 = (lane >> 4) & 3;
  const int K = kC;
  const bool is_xs = bm < 24;

  const bf16_t* Ag = Xb + (size_t)bm * 128 * K;
  const bf16_t* Bg = Wq + (is_xs ? (size_t)0 : (size_t)3072 * 1024) + (size_t)bn * 128 * K;

  // staged row (within 16-row group) = lane>>2; slot = lane&3; k-group = slot ^ ((row>>1)&3)
  // (row>>1)&3 == (lane>>3)&3  -> 8-row swizzle period = bank period -> 2-way max (free)
  const int srow32 = lane >> 2;
  const int scc32 = (((lane & 3) ^ ((lane >> 3) & 3)) << 3);

  auto stage = [&](int c, int kt) {
    const int k0 = kt * 32;
    bf16_t* Ab = smem + c * 4096;
    bf16_t* Bb = smem + 12288 + c * 4096;
    #pragma unroll
    for (int i = 0; i < 2; ++i) {
      const int row = w * 32 + i * 16 + srow32;
      gl16(Ag + (size_t)row * K + k0 + scc32, Ab + (w * 32 + i * 16) * 32);
      gl16(Bg + (size_t)row * K + k0 + scc32, Bb + (w * 32 + i * 16) * 32);
    }
  };

  f32x4_t acc[4][4] = {};
  const int nk = K / 32;   // 32
  stage(0, 0);             // 4 own loads
  stage(1, 1);             // +4 (8 outstanding/wave)

  for (int kt = 0; kt < nk; ++kt) {
    if (kt >= nk - 2) asm volatile("s_waitcnt vmcnt(0)" ::: "memory");
    else              asm volatile("s_waitcnt vmcnt(4)" ::: "memory");
    __builtin_amdgcn_s_barrier();
    __builtin_amdgcn_sched_barrier(0);
    if (kt + 2 < nk) stage((kt + 2) % 3, kt + 2);

    const int cur = kt % 3;
    const bf16_t* Ab = smem + cur * 4096;
    const bf16_t* Bb = smem + 12288 + cur * 4096;
    bf16x8_t a[4], b[4];
    #pragma unroll
    for (int m = 0; m < 4; ++m) {
      const int row = wr * 64 + m * 16 + l15;
      const int cc = (l4 * 8) ^ (((row >> 1) & 3) << 3);
      a[m] = *(const bf16x8_t*)&Ab[row * 32 + cc];
    }
    #pragma unroll
    for (int n = 0; n < 4; ++n) {
      const int row = wc * 64 + n * 16 + l15;
      const int cc = (l4 * 8) ^ (((row >> 1) & 3) << 3);
      b[n] = *(const bf16x8_t*)&Bb[row * 32 + cc];
    }
    #pragma unroll
    for (int m = 0; m < 4; ++m)
      #pragma unroll
      for (int n = 0; n < 4; ++n)
        acc[m][n] = __builtin_amdgcn_mfma_f32_16x16x32_bf16(a[m], b[n], acc[m][n], 0, 0, 0);
  }
  __builtin_amdgcn_s_barrier();

  // ---- fused epilogue (validated; acc layout unchanged) ----
  const int sec = bn >> 3;                 // 0=Q, 1=K, 2=V
  const int grow0 = bm * 128;
  int b, n0, seq_off; const float* cT; const float* sT;
  if (is_xs) { b = grow0 / 1536; n0 = grow0 - b * 1536; seq_off = 0; cT = cos1; sT = sin1; }
  else { const int g2 = grow0 - 3072; b = g2 >> 9; n0 = g2 & 511; seq_off = 1536; cT = cos2; sT = sin2; }
  const int h = (bn & 7) * 2 + wc;

  if (sec < 2) {
    const float* wsel = is_xs ? (sec == 0 ? xs_qw : xs_kw) : (sec == 0 ? au_qw : au_kw);
    float wv[4];
    #pragma unroll
    for (int n = 0; n < 4; ++n) wv[n] = wsel[n * 16 + l15];
    bf16_t* Out = (sec == 0 ? Qb : Kb) + (((size_t)b * kH + h) * kN + seq_off + n0) * kD;
    const float qscale = (sec == 0) ? 0.125f * 1.44269504088896f : 1.0f;
    #pragma unroll
    for (int m = 0; m < 4; ++m)
      #pragma unroll
      for (int r = 0; r < 4; ++r) {
        const int rl = wr * 64 + m * 16 + l4 * 4 + r;
        float ss = 0.0f;
        #pragma unroll
        for (int n = 0; n < 4; ++n) ss += acc[m][n][r] * acc[m][n][r];
        ss += __shfl_xor(ss, 1); ss += __shfl_xor(ss, 2);
        ss += __shfl_xor(ss, 4); ss += __shfl_xor(ss, 8);
        const float rinv = rsqrtf(ss * (1.0f / 64.0f) + 1e-5f);
        const int nrow = n0 + rl;
        #pragma unroll
        for (int n = 0; n < 4; ++n) {
          const int dd = n * 16 + l15;
          const float xn = acc[m][n][r] * rinv * wv[n];
          const float partner = __shfl_xor(xn, 1);
          if (!(l15 & 1)) {
            const float c = cT[(size_t)nrow * 64 + dd];
            const float s = sT[(size_t)nrow * 64 + dd];
            const float ve = (xn * c - partner * s) * qscale;
            const float vo = (partner * c + xn * s) * qscale;
            *(uint32_t*)&Out[(size_t)rl * kD + dd] = pack2bf(ve, vo);
          }
        }
      }
  } else {
    bf16_t* Lt = smem;                      // [128 cols][136] = 17408 elems <= 24576
    #pragma unroll
    for (int m = 0; m < 4; ++m)
      #pragma unroll
      for (int n = 0; n < 4; ++n) {
        const int col = wc * 64 + n * 16 + l15;
        #pragma unroll
        for (int j = 0; j < 2; ++j) {
          const int row = wr * 64 + m * 16 + l4 * 4 + j * 2;
          *(uint32_t*)&Lt[col * 136 + row] = pack2bf(acc[m][n][j * 2], acc[m][n][j * 2 + 1]);
        }
      }
    __syncthreads();
    const int seg = tid >> 1, half = tid & 1;
    const int hl = seg >> 6, dd = seg & 63;
    bf16_t* Vo = Vt + (((size_t)b * kH + (bn & 7) * 2 + hl) * kD + dd) * kN
                 + seq_off + n0 + half * 64;
    #pragma unroll
    for (int jj = 0; jj < 8; ++jj)
      *(bf16x8_t*)&Vo[jj * 8] = *(const bf16x8_t*)&Lt[seg * 136 + half * 64 + jj * 8];
  }
}

// ---------- output projection (UNCHANGED - control) ----------
__global__ __launch_bounds__(256, 2)
void proj_gemm(const bf16_t* __restrict__ Ob, const bf16_t* __restrict__ Wp,
               const float* __restrict__ bxs, const float* __restrict__ bau,
               float* __restrict__ out)
{
  __shared__ __align__(16) bf16_t smem[32768];
  const int tid = threadIdx.x, lane = tid & 63, w = tid >> 6;
  const int wr = w >> 1, wc = w & 1;
  const int bm = blockIdx.x, bn = blockIdx.y;
  const int l15 = lane & 15, l4 = (lane >> 4) & 3;
  const int K = kC, N = kC;

  const int grow = bm * 128;
  const int b = grow >> 11, n0r = grow & 2047;
  const bf16_t* Bg; const float* bias; float* Cg;
  if (n0r < kN1) { Bg = Wp; bias = bxs; Cg = out + ((size_t)b * kN1 + n0r) * kC; }
  else { Bg = Wp + (size_t)1024 * 1024; bias = bau;
         Cg = out + (size_t)kB * kN1 * kC + ((size_t)b * kN2 + (n0r - kN1)) * kC; }
  Bg += (size_t)bn * 128 * K;
  const bf16_t* Ag = Ob + (size_t)grow * K;

  const int srow_l = lane >> 3;
  const int scc = (((lane & 7) ^ ((lane >> 3) & 7)) << 3);

  auto stage = [&](int c, int kt) {
    const int k0 = kt * BK;
    bf16_t* Ab = smem + c * 8192;
    bf16_t* Bb = smem + 16384 + c * 8192;
    #pragma unroll
    for (int i = 0; i < 4; ++i) {
      const int row = w * 32 + i * 8 + srow_l;
      gl16(Ag + (size_t)row * K + k0 + scc, Ab + (w * 32 + i * 8) * 64);
      gl16(Bg + (size_t)row * K + k0 + scc, Bb + (w * 32 + i * 8) * 64);
    }
  };

  f32x4_t acc[4][4] = {};
  const int nk = K / BK;
  stage(0, 0);
  asm volatile("s_waitcnt vmcnt(0)" ::: "memory");
  __syncthreads();

  int cur = 0;
  for (int kt = 0; kt < nk; ++kt) {
    if (kt + 1 < nk) stage(cur ^ 1, kt + 1);
    const bf16_t* Ab = smem + cur * 8192;
    const bf16_t* Bb = smem + 16384 + cur * 8192;
    #pragma unroll
    for (int kk = 0; kk < 2; ++kk) {
      bf16x8_t a[4], bfr[4];
      #pragma unroll
      for (int m = 0; m < 4; ++m) {
        const int row = wr * 64 + m * 16 + l15;
        const int cc = (kk * 32 + l4 * 8) ^ ((row & 7) << 3);
        a[m] = *(const bf16x8_t*)&Ab[row * 64 + cc];
      }
      #pragma unroll
      for (int n = 0; n < 4; ++n) {
        const int row = wc * 64 + n * 16 + l15;
        const int cc = (kk * 32 + l4 * 8) ^ ((row & 7) << 3);
        bfr[n] = *(const bf16x8_t*)&Bb[row * 64 + cc];
      }
      #pragma unroll
      for (int m = 0; m < 4; ++m)
        #pragma unroll
        for (int n = 0; n < 4; ++n)
          acc[m][n] = __builtin_amdgcn_mfma_f32_16x16x32_bf16(a[m], bfr[n], acc[m][n], 0, 0, 0);
    }
    asm volatile("s_waitcnt vmcnt(0)" ::: "memory");
    __syncthreads();
    cur ^= 1;
  }

  float bv[4];
  #pragma unroll
  for (int n = 0; n < 4; ++n) bv[n] = bias[bn * 128 + wc * 64 + n * 16 + l15];
  #pragma unroll
  for (int m = 0; m < 4; ++m)
    #pragma unroll
    for (int n = 0; n < 4; ++n) {
      const int col = bn * 128 + wc * 64 + n * 16 + l15;
      #pragma unroll
      for (int r = 0; r < 4; ++r) {
        const int row = wr * 64 + m * 16 + l4 * 4 + r;
        Cg[(size_t)row * N + col] = acc[m][n][r] + bv[n];
      }
    }
}

// ---- Flash attention (UNCHANGED, validated) ----
__global__ __launch_bounds__(512, 2)
void flash_attn(const bf16_t* __restrict__ Q, const bf16_t* __restrict__ K,
                const bf16_t* __restrict__ Vt, bf16_t* __restrict__ O)
{
  __shared__ __align__(16) bf16_t smem[18432];
  const int tid = threadIdx.x, lane = tid & 63, w = tid >> 6;
  const int l31 = lane & 31, hi8 = ((lane >> 5) << 3), hi4 = ((lane >> 5) << 2);
  const int lin = blockIdx.x;
  const int qt = lin >> 5, hid = lin & 31;
  const int h = hid & 15, b = hid >> 4;
  const size_t headoff = ((size_t)(b * kH + h)) * kN * kD;
  const bf16_t* Kg = K + headoff;
  const bf16_t* Vg = Vt + headoff;

  bf16x8_t qf[4];
  {
    const bf16_t* Qg = Q + headoff + (size_t)(qt * 256 + w * 32 + l31) * kD + hi8;
    #pragma unroll
    for (int ks = 0; ks < 4; ++ks) qf[ks] = *(const bf16x8_t*)(Qg + ks * 16);
  }
  bf16x8_t onesv;
  #pragma unroll
  for (int j = 0; j < 8; ++j) onesv[j] = (bf16_t)1.0f;

  const int srow = tid >> 3, sc = (tid & 7) * 8;
  bf16x8_t kreg = *(const bf16x8_t*)(Kg + srow * kD + sc);
  bf16x8_t vreg = *(const bf16x8_t*)(Vg + (size_t)srow * kN + sc);

  f32x16_t oA0 = {}, oA1 = {}, accl = {};

  for (int kt = 0; kt < kN / 64; ++kt) {
    const int cur = kt & 1;
    bf16_t* Kc = smem + cur * 4608;
    bf16_t* Vc = smem + 9216 + cur * 4608;
    *(bf16x8_t*)&Kc[srow * LDT + sc] = kreg;
    *(bf16x8_t*)&Vc[srow * LDT + sc] = vreg;
    if (kt + 1 < kN / 64) {
      kreg = *(const bf16x8_t*)(Kg + (size_t)(kt + 1) * 64 * kD + srow * kD + sc);
      vreg = *(const bf16x8_t*)(Vg + (size_t)srow * kN + (kt + 1) * 64 + sc);
    }
    __syncthreads();

    f32x16_t s0 = {}, s1 = {};
    #pragma unroll
    for (int ks = 0; ks < 4; ++ks) {
      bf16x8_t k0 = *(const bf16x8_t*)&Kc[l31 * LDT + ks * 16 + hi8];
      bf16x8_t k1 = *(const bf16x8_t*)&Kc[(32 + l31) * LDT + ks * 16 + hi8];
      s0 = __builtin_amdgcn_mfma_f32_32x32x16_bf16(k0, qf[ks], s0, 0, 0, 0);
      s1 = __builtin_amdgcn_mfma_f32_32x32x16_bf16(k1, qf[ks], s1, 0, 0, 0);
    }

    #pragma unroll
    for (int i = 0; i < 16; ++i) {
      s0[i] = __builtin_amdgcn_exp2f(s0[i]);
      s1[i] = __builtin_amdgcn_exp2f(s1[i]);
    }

    union PW { uint32_t wd[4]; bf16x8_t v; } pf[4];
    #pragma unroll
    for (int o = 0; o < 2; ++o) {
      #pragma unroll
      for (int hh = 0; hh < 2; ++hh) {
        const int h8 = hh * 8, ks = o * 2 + hh;
        float p0, p1, p2, p3, p4, p5, p6, p7;
        if (o == 0) {
          p0 = s0[h8+0]; p1 = s0[h8+1]; p2 = s0[h8+2]; p3 = s0[h8+3];
          p4 = s0[h8+4]; p5 = s0[h8+5]; p6 = s0[h8+6]; p7 = s0[h8+7];
        } else {
          p0 = s1[h8+0]; p1 = s1[h8+1]; p2 = s1[h8+2]; p3 = s1[h8+3];
          p4 = s1[h8+4]; p5 = s1[h8+5]; p6 = s1[h8+6]; p7 = s1[h8+7];
        }
        uint32_t xw  = pack2bf(p0, p1), x2 = pack2bf(p2, p3);
        uint32_t yw  = pack2bf(p4, p5), y2 = pack2bf(p6, p7);
        pl32_swap(xw, yw);
        pl32_swap(x2, y2);
        pf[ks].wd[0] = xw; pf[ks].wd[1] = x2; pf[ks].wd[2] = yw; pf[ks].wd[3] = y2;
      }
    }

    #pragma unroll
    for (int ks = 0; ks < 4; ++ks) {
      bf16x8_t v0 = *(const bf16x8_t*)&Vc[l31 * LDT + ks * 16 + hi8];
      bf16x8_t v1 = *(const bf16x8_t*)&Vc[(32 + l31) * LDT + ks * 16 + hi8];
      oA0 = __builtin_amdgcn_mfma_f32_32x32x16_bf16(v0, pf[ks].v, oA0, 0, 0, 0);
      oA1 = __builtin_amdgcn_mfma_f32_32x32x16_bf16(v1, pf[ks].v, oA1, 0, 0, 0);
      accl = __builtin_amdgcn_mfma_f32_32x32x16_bf16(onesv, pf[ks].v, accl, 0, 0, 0);
    }
  }

  __syncthreads();
  bf16_t* Ow = smem + w * 2304;
  const float inv = 1.0f / accl[0];
  #pragma unroll
  for (int db = 0; db < 2; ++db) {
    f32x16_t o = db ? oA1 : oA0;
    #pragma unroll
    for (int rp = 0; rp < 8; ++rp) {
      const int d = db * 32 + ((rp & 1) << 1) + ((rp >> 1) << 3) + hi4;
      *(uint32_t*)&Ow[l31 * LDT + d] = pack2bf(o[2 * rp] * inv, o[2 * rp + 1] * inv);
    }
  }
  const int rq = lane >> 1, half = lane & 1;
  bf16x8_t r0 = *(const bf16x8_t*)&Ow[rq * LDT + half * 32];
  bf16x8_t r1 = *(const bf16x8_t*)&Ow[rq * LDT + half * 32 + 8];
  bf16x8_t r2 = *(const bf16x8_t*)&Ow[rq * LDT + half * 32 + 16];
  bf16x8_t r3 = *(const bf16x8_t*)&Ow[rq * LDT + half * 32 + 24];
  bf16_t* Og = O + ((size_t)b * kN + qt * 256 + w * 32 + rq) * kC + h * kD + half * 32;
  *(bf16x8_t*)&Og[0]  = r0;
  *(bf16x8_t*)&Og[8]  = r1;
  *(bf16x8_t*)&Og[16] = r2;
  *(bf16x8_t*)&Og[24] = r3;
}

// ---------------- launch ----------------
extern "C" void kernel_launch(void* const* d_in, const int* in_sizes, int n_in,
                              void* d_out, int out_size, void* d_ws, size_t ws_size,
                              hipStream_t stream) {
  const float* x    = (const float*)d_in[1];
  const float* y    = (const float*)d_in[2];
  const float* cos1 = (const float*)d_in[3];
  const float* sin1 = (const float*)d_in[4];
  const float* cos2 = (const float*)d_in[5];
  const float* sin2 = (const float*)d_in[6];
  const float* Wqkv_xs = (const float*)d_in[7];
  const float* Wqkv_au = (const float*)d_in[8];
  const float* xs_q_w  = (const float*)d_in[9];
  const float* xs_k_w  = (const float*)d_in[10];
  const float* au_q_w  = (const float*)d_in[11];
  const float* au_k_w  = (const float*)d_in[12];
  const float* Wxs = (const float*)d_in[13];
  const float* bxs = (const float*)d_in[14];
  const float* Wau = (const float*)d_in[15];
  const float* bau = (const float*)d_in[16];
  float* out = (float*)d_out;

  char* ws = (char*)d_ws;
  bf16_t* Xb = (bf16_t*)(ws);
  bf16_t* Wq = (bf16_t*)(ws + 8388608);
  bf16_t* Wp = (bf16_t*)(ws + 20971520);
  bf16_t* Qb = (bf16_t*)(ws + 25165824);
  bf16_t* Kb = (bf16_t*)(ws + 33554432);
  bf16_t* Vt = (bf16_t*)(ws + 41943040);
  bf16_t* Ob = (bf16_t*)(ws + 50331648);

  cvt_bf16<<<dim3(768), dim3(256), 0, stream>>>(x, y, Wqkv_xs, Wqkv_au, Wxs, Wau, Xb, Wq, Wp);
  qkv_gemm<<<dim3(32, 24), dim3(256), 0, stream>>>(Xb, Wq, cos1, sin1, cos2, sin2,
      xs_q_w, xs_k_w, au_q_w, au_k_w, Qb, Kb, Vt);
  flash_attn<<<dim3(256), dim3(512), 0, stream>>>(Qb, Kb, Vt, Ob);
  proj_gemm<<<dim3(32, 8), dim3(256), 0, stream>>>(Ob, Wp, bxs, bau, out);
}

// Round 15
// 124.167 us; speedup vs baseline: 1.0141x; 1.0141x over previous
//
#include <hip/hip_runtime.h>
#include <hip/hip_bf16.h>

typedef __bf16 bf16_t;
typedef bf16_t bf16x4_t __attribute__((ext_vector_type(4)));
typedef bf16_t bf16x8_t __attribute__((ext_vector_type(8)));
typedef float f32x4_t __attribute__((ext_vector_type(4)));
typedef float f32x16_t __attribute__((ext_vector_type(16)));

constexpr int kB = 2, kN1 = 1536, kN2 = 512, kN = 2048, kC = 1024, kH = 16, kD = 64;
constexpr int BK = 64, LDT = 72;

__device__ inline uint32_t pack2bf(float a, float b) {
  union { bf16_t h[2]; uint32_t u; } t;
  t.h[0] = (bf16_t)a; t.h[1] = (bf16_t)b;
  return t.u;
}
__device__ inline void pl32_swap(uint32_t& a, uint32_t& b) {
  asm volatile("v_permlane32_swap_b32 %0, %1" : "+v"(a), "+v"(b));
}
__device__ __forceinline__ void gl16(const bf16_t* g, bf16_t* l) {
  __builtin_amdgcn_global_load_lds(
      (const __attribute__((address_space(1))) unsigned int*)g,
      (__attribute__((address_space(3))) unsigned int*)l, 16, 0, 0);
}

// ---------------- one-time f32 -> bf16 conversion ----------------
__global__ __launch_bounds__(256)
void cvt_bf16(const float* __restrict__ x, const float* __restrict__ y,
              const float* __restrict__ wqx, const float* __restrict__ wqa,
              const float* __restrict__ wpx, const float* __restrict__ wpa,
              bf16_t* __restrict__ Xb, bf16_t* __restrict__ Wq, bf16_t* __restrict__ Wp)
{
  const int bid = blockIdx.x;
  const float* src; bf16_t* dst; size_t off;
  if (bid < 192)      { src = x;   dst = Xb;           off = (size_t)bid * 16384; }
  else if (bid < 256) { src = y;   dst = Xb + 3145728; off = (size_t)(bid - 192) * 16384; }
  else if (bid < 448) { src = wqx; dst = Wq;           off = (size_t)(bid - 256) * 16384; }
  else if (bid < 640) { src = wqa; dst = Wq + 3145728; off = (size_t)(bid - 448) * 16384; }
  else if (bid < 704) { src = wpx; dst = Wp;           off = (size_t)(bid - 640) * 16384; }
  else                { src = wpa; dst = Wp + 1048576; off = (size_t)(bid - 704) * 16384; }
  src += off; dst += off;
  const int t = threadIdx.x;
  #pragma unroll
  for (int i = 0; i < 16; ++i) {
    const int e = (t + i * 256) * 4;
    f32x4_t v = *(const f32x4_t*)(src + e);
    bf16x4_t o;
    #pragma unroll
    for (int j = 0; j < 4; ++j) o[j] = (bf16_t)v[j];
    *(bf16x4_t*)(dst + e) = o;
  }
}

// ---- QKV GEMM: 128x128, BK=32, 3-stage buffers, raw barrier + counted vmcnt(4)
//      + T5 setprio around MFMA cluster ----
__global__ __launch_bounds__(256, 3)
void qkv_gemm(const bf16_t* __restrict__ Xb, const bf16_t* __restrict__ Wq,
              const float* __restrict__ cos1, const float* __restrict__ sin1,
              const float* __restrict__ cos2, const float* __restrict__ sin2,
              const float* __restrict__ xs_qw, const float* __restrict__ xs_kw,
              const float* __restrict__ au_qw, const float* __restrict__ au_kw,
              bf16_t* __restrict__ Qb, bf16_t* __restrict__ Kb, bf16_t* __restrict__ Vt)
{
  __shared__ __align__(16) bf16_t smem[24576];  // A bufs x3 [0,12288) | B bufs x3 [12288,24576)
  const int tid = threadIdx.x, lane = tid & 63, w = tid >> 6;
  const int wr = w >> 1, wc = w & 1;
  const int bm = blockIdx.x, bn = blockIdx.y;
  const int l15 = lane & 15, l4 = (lane >> 4) & 3;
  const int K = kC;
  const bool is_xs = bm < 24;

  const bf16_t* Ag = Xb + (size_t)bm * 128 * K;
  const bf16_t* Bg = Wq + (is_xs ? (size_t)0 : (size_t)3072 * 1024) + (size_t)bn * 128 * K;

  const int srow32 = lane >> 2;
  const int scc32 = (((lane & 3) ^ ((lane >> 3) & 3)) << 3);

  auto stage = [&](int c, int kt) {
    const int k0 = kt * 32;
    bf16_t* Ab = smem + c * 4096;
    bf16_t* Bb = smem + 12288 + c * 4096;
    #pragma unroll
    for (int i = 0; i < 2; ++i) {
      const int row = w * 32 + i * 16 + srow32;
      gl16(Ag + (size_t)row * K + k0 + scc32, Ab + (w * 32 + i * 16) * 32);
      gl16(Bg + (size_t)row * K + k0 + scc32, Bb + (w * 32 + i * 16) * 32);
    }
  };

  f32x4_t acc[4][4] = {};
  const int nk = K / 32;   // 32
  stage(0, 0);
  stage(1, 1);

  for (int kt = 0; kt < nk; ++kt) {
    if (kt >= nk - 2) asm volatile("s_waitcnt vmcnt(0)" ::: "memory");
    else              asm volatile("s_waitcnt vmcnt(4)" ::: "memory");
    __builtin_amdgcn_s_barrier();
    __builtin_amdgcn_sched_barrier(0);
    if (kt + 2 < nk) stage((kt + 2) % 3, kt + 2);

    const int cur = kt % 3;
    const bf16_t* Ab = smem + cur * 4096;
    const bf16_t* Bb = smem + 12288 + cur * 4096;
    bf16x8_t a[4], b[4];
    #pragma unroll
    for (int m = 0; m < 4; ++m) {
      const int row = wr * 64 + m * 16 + l15;
      const int cc = (l4 * 8) ^ (((row >> 1) & 3) << 3);
      a[m] = *(const bf16x8_t*)&Ab[row * 32 + cc];
    }
    #pragma unroll
    for (int n = 0; n < 4; ++n) {
      const int row = wc * 64 + n * 16 + l15;
      const int cc = (l4 * 8) ^ (((row >> 1) & 3) << 3);
      b[n] = *(const bf16x8_t*)&Bb[row * 32 + cc];
    }
    __builtin_amdgcn_s_setprio(1);          // T5: favor MFMA-entering wave
    #pragma unroll
    for (int m = 0; m < 4; ++m)
      #pragma unroll
      for (int n = 0; n < 4; ++n)
        acc[m][n] = __builtin_amdgcn_mfma_f32_16x16x32_bf16(a[m], b[n], acc[m][n], 0, 0, 0);
    __builtin_amdgcn_s_setprio(0);
  }
  __builtin_amdgcn_s_barrier();

  // ---- fused epilogue (validated; acc layout unchanged) ----
  const int sec = bn >> 3;                 // 0=Q, 1=K, 2=V
  const int grow0 = bm * 128;
  int b, n0, seq_off; const float* cT; const float* sT;
  if (is_xs) { b = grow0 / 1536; n0 = grow0 - b * 1536; seq_off = 0; cT = cos1; sT = sin1; }
  else { const int g2 = grow0 - 3072; b = g2 >> 9; n0 = g2 & 511; seq_off = 1536; cT = cos2; sT = sin2; }
  const int h = (bn & 7) * 2 + wc;

  if (sec < 2) {
    const float* wsel = is_xs ? (sec == 0 ? xs_qw : xs_kw) : (sec == 0 ? au_qw : au_kw);
    float wv[4];
    #pragma unroll
    for (int n = 0; n < 4; ++n) wv[n] = wsel[n * 16 + l15];
    bf16_t* Out = (sec == 0 ? Qb : Kb) + (((size_t)b * kH + h) * kN + seq_off + n0) * kD;
    const float qscale = (sec == 0) ? 0.125f * 1.44269504088896f : 1.0f;
    #pragma unroll
    for (int m = 0; m < 4; ++m)
      #pragma unroll
      for (int r = 0; r < 4; ++r) {
        const int rl = wr * 64 + m * 16 + l4 * 4 + r;
        float ss = 0.0f;
        #pragma unroll
        for (int n = 0; n < 4; ++n) ss += acc[m][n][r] * acc[m][n][r];
        ss += __shfl_xor(ss, 1); ss += __shfl_xor(ss, 2);
        ss += __shfl_xor(ss, 4); ss += __shfl_xor(ss, 8);
        const float rinv = rsqrtf(ss * (1.0f / 64.0f) + 1e-5f);
        const int nrow = n0 + rl;
        #pragma unroll
        for (int n = 0; n < 4; ++n) {
          const int dd = n * 16 + l15;
          const float xn = acc[m][n][r] * rinv * wv[n];
          const float partner = __shfl_xor(xn, 1);
          if (!(l15 & 1)) {
            const float c = cT[(size_t)nrow * 64 + dd];
            const float s = sT[(size_t)nrow * 64 + dd];
            const float ve = (xn * c - partner * s) * qscale;
            const float vo = (partner * c + xn * s) * qscale;
            *(uint32_t*)&Out[(size_t)rl * kD + dd] = pack2bf(ve, vo);
          }
        }
      }
  } else {
    bf16_t* Lt = smem;                      // [128 cols][136] = 17408 elems <= 24576
    #pragma unroll
    for (int m = 0; m < 4; ++m)
      #pragma unroll
      for (int n = 0; n < 4; ++n) {
        const int col = wc * 64 + n * 16 + l15;
        #pragma unroll
        for (int j = 0; j < 2; ++j) {
          const int row = wr * 64 + m * 16 + l4 * 4 + j * 2;
          *(uint32_t*)&Lt[col * 136 + row] = pack2bf(acc[m][n][j * 2], acc[m][n][j * 2 + 1]);
        }
      }
    __syncthreads();
    const int seg = tid >> 1, half = tid & 1;
    const int hl = seg >> 6, dd = seg & 63;
    bf16_t* Vo = Vt + (((size_t)b * kH + (bn & 7) * 2 + hl) * kD + dd) * kN
                 + seq_off + n0 + half * 64;
    #pragma unroll
    for (int jj = 0; jj < 8; ++jj)
      *(bf16x8_t*)&Vo[jj * 8] = *(const bf16x8_t*)&Lt[seg * 136 + half * 64 + jj * 8];
  }
}

// ---------- output projection (control; + T5 setprio only) ----------
__global__ __launch_bounds__(256, 2)
void proj_gemm(const bf16_t* __restrict__ Ob, const bf16_t* __restrict__ Wp,
               const float* __restrict__ bxs, const float* __restrict__ bau,
               float* __restrict__ out)
{
  __shared__ __align__(16) bf16_t smem[32768];
  const int tid = threadIdx.x, lane = tid & 63, w = tid >> 6;
  const int wr = w >> 1, wc = w & 1;
  const int bm = blockIdx.x, bn = blockIdx.y;
  const int l15 = lane & 15, l4 = (lane >> 4) & 3;
  const int K = kC, N = kC;

  const int grow = bm * 128;
  const int b = grow >> 11, n0r = grow & 2047;
  const bf16_t* Bg; const float* bias; float* Cg;
  if (n0r < kN1) { Bg = Wp; bias = bxs; Cg = out + ((size_t)b * kN1 + n0r) * kC; }
  else { Bg = Wp + (size_t)1024 * 1024; bias = bau;
         Cg = out + (size_t)kB * kN1 * kC + ((size_t)b * kN2 + (n0r - kN1)) * kC; }
  Bg += (size_t)bn * 128 * K;
  const bf16_t* Ag = Ob + (size_t)grow * K;

  const int srow_l = lane >> 3;
  const int scc = (((lane & 7) ^ ((lane >> 3) & 7)) << 3);

  auto stage = [&](int c, int kt) {
    const int k0 = kt * BK;
    bf16_t* Ab = smem + c * 8192;
    bf16_t* Bb = smem + 16384 + c * 8192;
    #pragma unroll
    for (int i = 0; i < 4; ++i) {
      const int row = w * 32 + i * 8 + srow_l;
      gl16(Ag + (size_t)row * K + k0 + scc, Ab + (w * 32 + i * 8) * 64);
      gl16(Bg + (size_t)row * K + k0 + scc, Bb + (w * 32 + i * 8) * 64);
    }
  };

  f32x4_t acc[4][4] = {};
  const int nk = K / BK;
  stage(0, 0);
  asm volatile("s_waitcnt vmcnt(0)" ::: "memory");
  __syncthreads();

  int cur = 0;
  for (int kt = 0; kt < nk; ++kt) {
    if (kt + 1 < nk) stage(cur ^ 1, kt + 1);
    const bf16_t* Ab = smem + cur * 8192;
    const bf16_t* Bb = smem + 16384 + cur * 8192;
    #pragma unroll
    for (int kk = 0; kk < 2; ++kk) {
      bf16x8_t a[4], bfr[4];
      #pragma unroll
      for (int m = 0; m < 4; ++m) {
        const int row = wr * 64 + m * 16 + l15;
        const int cc = (kk * 32 + l4 * 8) ^ ((row & 7) << 3);
        a[m] = *(const bf16x8_t*)&Ab[row * 64 + cc];
      }
      #pragma unroll
      for (int n = 0; n < 4; ++n) {
        const int row = wc * 64 + n * 16 + l15;
        const int cc = (kk * 32 + l4 * 8) ^ ((row & 7) << 3);
        bfr[n] = *(const bf16x8_t*)&Bb[row * 64 + cc];
      }
      __builtin_amdgcn_s_setprio(1);
      #pragma unroll
      for (int m = 0; m < 4; ++m)
        #pragma unroll
        for (int n = 0; n < 4; ++n)
          acc[m][n] = __builtin_amdgcn_mfma_f32_16x16x32_bf16(a[m], bfr[n], acc[m][n], 0, 0, 0);
      __builtin_amdgcn_s_setprio(0);
    }
    asm volatile("s_waitcnt vmcnt(0)" ::: "memory");
    __syncthreads();
    cur ^= 1;
  }

  float bv[4];
  #pragma unroll
  for (int n = 0; n < 4; ++n) bv[n] = bias[bn * 128 + wc * 64 + n * 16 + l15];
  #pragma unroll
  for (int m = 0; m < 4; ++m)
    #pragma unroll
    for (int n = 0; n < 4; ++n) {
      const int col = bn * 128 + wc * 64 + n * 16 + l15;
      #pragma unroll
      for (int r = 0; r < 4; ++r) {
        const int row = wr * 64 + m * 16 + l4 * 4 + r;
        Cg[(size_t)row * N + col] = acc[m][n][r] + bv[n];
      }
    }
}

// ---- Flash attention (validated + T5 setprio around MFMA clusters) ----
__global__ __launch_bounds__(512, 2)
void flash_attn(const bf16_t* __restrict__ Q, const bf16_t* __restrict__ K,
                const bf16_t* __restrict__ Vt, bf16_t* __restrict__ O)
{
  __shared__ __align__(16) bf16_t smem[18432];
  const int tid = threadIdx.x, lane = tid & 63, w = tid >> 6;
  const int l31 = lane & 31, hi8 = ((lane >> 5) << 3), hi4 = ((lane >> 5) << 2);
  const int lin = blockIdx.x;
  const int qt = lin >> 5, hid = lin & 31;
  const int h = hid & 15, b = hid >> 4;
  const size_t headoff = ((size_t)(b * kH + h)) * kN * kD;
  const bf16_t* Kg = K + headoff;
  const bf16_t* Vg = Vt + headoff;

  bf16x8_t qf[4];
  {
    const bf16_t* Qg = Q + headoff + (size_t)(qt * 256 + w * 32 + l31) * kD + hi8;
    #pragma unroll
    for (int ks = 0; ks < 4; ++ks) qf[ks] = *(const bf16x8_t*)(Qg + ks * 16);
  }
  bf16x8_t onesv;
  #pragma unroll
  for (int j = 0; j < 8; ++j) onesv[j] = (bf16_t)1.0f;

  const int srow = tid >> 3, sc = (tid & 7) * 8;
  bf16x8_t kreg = *(const bf16x8_t*)(Kg + srow * kD + sc);
  bf16x8_t vreg = *(const bf16x8_t*)(Vg + (size_t)srow * kN + sc);

  f32x16_t oA0 = {}, oA1 = {}, accl = {};

  for (int kt = 0; kt < kN / 64; ++kt) {
    const int cur = kt & 1;
    bf16_t* Kc = smem + cur * 4608;
    bf16_t* Vc = smem + 9216 + cur * 4608;
    *(bf16x8_t*)&Kc[srow * LDT + sc] = kreg;
    *(bf16x8_t*)&Vc[srow * LDT + sc] = vreg;
    if (kt + 1 < kN / 64) {
      kreg = *(const bf16x8_t*)(Kg + (size_t)(kt + 1) * 64 * kD + srow * kD + sc);
      vreg = *(const bf16x8_t*)(Vg + (size_t)srow * kN + (kt + 1) * 64 + sc);
    }
    __syncthreads();

    f32x16_t s0 = {}, s1 = {};
    __builtin_amdgcn_s_setprio(1);
    #pragma unroll
    for (int ks = 0; ks < 4; ++ks) {
      bf16x8_t k0 = *(const bf16x8_t*)&Kc[l31 * LDT + ks * 16 + hi8];
      bf16x8_t k1 = *(const bf16x8_t*)&Kc[(32 + l31) * LDT + ks * 16 + hi8];
      s0 = __builtin_amdgcn_mfma_f32_32x32x16_bf16(k0, qf[ks], s0, 0, 0, 0);
      s1 = __builtin_amdgcn_mfma_f32_32x32x16_bf16(k1, qf[ks], s1, 0, 0, 0);
    }
    __builtin_amdgcn_s_setprio(0);

    #pragma unroll
    for (int i = 0; i < 16; ++i) {
      s0[i] = __builtin_amdgcn_exp2f(s0[i]);
      s1[i] = __builtin_amdgcn_exp2f(s1[i]);
    }

    union PW { uint32_t wd[4]; bf16x8_t v; } pf[4];
    #pragma unroll
    for (int o = 0; o < 2; ++o) {
      #pragma unroll
      for (int hh = 0; hh < 2; ++hh) {
        const int h8 = hh * 8, ks = o * 2 + hh;
        float p0, p1, p2, p3, p4, p5, p6, p7;
        if (o == 0) {
          p0 = s0[h8+0]; p1 = s0[h8+1]; p2 = s0[h8+2]; p3 = s0[h8+3];
          p4 = s0[h8+4]; p5 = s0[h8+5]; p6 = s0[h8+6]; p7 = s0[h8+7];
        } else {
          p0 = s1[h8+0]; p1 = s1[h8+1]; p2 = s1[h8+2]; p3 = s1[h8+3];
          p4 = s1[h8+4]; p5 = s1[h8+5]; p6 = s1[h8+6]; p7 = s1[h8+7];
        }
        uint32_t xw  = pack2bf(p0, p1), x2 = pack2bf(p2, p3);
        uint32_t yw  = pack2bf(p4, p5), y2 = pack2bf(p6, p7);
        pl32_swap(xw, yw);
        pl32_swap(x2, y2);
        pf[ks].wd[0] = xw; pf[ks].wd[1] = x2; pf[ks].wd[2] = yw; pf[ks].wd[3] = y2;
      }
    }

    __builtin_amdgcn_s_setprio(1);
    #pragma unroll
    for (int ks = 0; ks < 4; ++ks) {
      bf16x8_t v0 = *(const bf16x8_t*)&Vc[l31 * LDT + ks * 16 + hi8];
      bf16x8_t v1 = *(const bf16x8_t*)&Vc[(32 + l31) * LDT + ks * 16 + hi8];
      oA0 = __builtin_amdgcn_mfma_f32_32x32x16_bf16(v0, pf[ks].v, oA0, 0, 0, 0);
      oA1 = __builtin_amdgcn_mfma_f32_32x32x16_bf16(v1, pf[ks].v, oA1, 0, 0, 0);
      accl = __builtin_amdgcn_mfma_f32_32x32x16_bf16(onesv, pf[ks].v, accl, 0, 0, 0);
    }
    __builtin_amdgcn_s_setprio(0);
  }

  __syncthreads();
  bf16_t* Ow = smem + w * 2304;
  const float inv = 1.0f / accl[0];
  #pragma unroll
  for (int db = 0; db < 2; ++db) {
    f32x16_t o = db ? oA1 : oA0;
    #pragma unroll
    for (int rp = 0; rp < 8; ++rp) {
      const int d = db * 32 + ((rp & 1) << 1) + ((rp >> 1) << 3) + hi4;
      *(uint32_t*)&Ow[l31 * LDT + d] = pack2bf(o[2 * rp] * inv, o[2 * rp + 1] * inv);
    }
  }
  const int rq = lane >> 1, half = lane & 1;
  bf16x8_t r0 = *(const bf16x8_t*)&Ow[rq * LDT + half * 32];
  bf16x8_t r1 = *(const bf16x8_t*)&Ow[rq * LDT + half * 32 + 8];
  bf16x8_t r2 = *(const bf16x8_t*)&Ow[rq * LDT + half * 32 + 16];
  bf16x8_t r3 = *(const bf16x8_t*)&Ow[rq * LDT + half * 32 + 24];
  bf16_t* Og = O + ((size_t)b * kN + qt * 256 + w * 32 + rq) * kC + h * kD + half * 32;
  *(bf16x8_t*)&Og[0]  = r0;
  *(bf16x8_t*)&Og[8]  = r1;
  *(bf16x8_t*)&Og[16] = r2;
  *(bf16x8_t*)&Og[24] = r3;
}

// ---------------- launch ----------------
extern "C" void kernel_launch(void* const* d_in, const int* in_sizes, int n_in,
                              void* d_out, int out_size, void* d_ws, size_t ws_size,
                              hipStream_t stream) {
  const float* x    = (const float*)d_in[1];
  const float* y    = (const float*)d_in[2];
  const float* cos1 = (const float*)d_in[3];
  const float* sin1 = (const float*)d_in[4];
  const float* cos2 = (const float*)d_in[5];
  const float* sin2 = (const float*)d_in[6];
  const float* Wqkv_xs = (const float*)d_in[7];
  const float* Wqkv_au = (const float*)d_in[8];
  const float* xs_q_w  = (const float*)d_in[9];
  const float* xs_k_w  = (const float*)d_in[10];
  const float* au_q_w  = (const float*)d_in[11];
  const float* au_k_w  = (const float*)d_in[12];
  const float* Wxs = (const float*)d_in[13];
  const float* bxs = (const float*)d_in[14];
  const float* Wau = (const float*)d_in[15];
  const float* bau = (const float*)d_in[16];
  float* out = (float*)d_out;

  char* ws = (char*)d_ws;
  bf16_t* Xb = (bf16_t*)(ws);
  bf16_t* Wq = (bf16_t*)(ws + 8388608);
  bf16_t* Wp = (bf16_t*)(ws + 20971520);
  bf16_t* Qb = (bf16_t*)(ws + 25165824);
  bf16_t* Kb = (bf16_t*)(ws + 33554432);
  bf16_t* Vt = (bf16_t*)(ws + 41943040);
  bf16_t* Ob = (bf16_t*)(ws + 50331648);

  cvt_bf16<<<dim3(768), dim3(256), 0, stream>>>(x, y, Wqkv_xs, Wqkv_au, Wxs, Wau, Xb, Wq, Wp);
  qkv_gemm<<<dim3(32, 24), dim3(256), 0, stream>>>(Xb, Wq, cos1, sin1, cos2, sin2,
      xs_q_w, xs_k_w, au_q_w, au_k_w, Qb, Kb, Vt);
  flash_attn<<<dim3(256), dim3(512), 0, stream>>>(Qb, Kb, Vt, Ob);
  proj_gemm<<<dim3(32, 8), dim3(256), 0, stream>>>(Ob, Wp, bxs, bau, out);
}